// Round 2
// baseline (1251.368 us; speedup 1.0000x reference)
//
#include <hip/hip_runtime.h>
#include <hip/hip_bf16.h>
#include <stdint.h>

// Problem: out (16384x4096 fp32) = x (16384x4096 fp32) @ W^T + bias,
// W (4096x4096) = sum_b kron-structured from A (8,64,64), B (8,64,64).
#define M_DIM 16384
#define N_DIM 4096
#define K_DIM 4096

typedef short short8 __attribute__((ext_vector_type(8)));      // 8 bf16 MFMA frag
typedef unsigned short ushort8 __attribute__((ext_vector_type(8)));
typedef float f32x4 __attribute__((ext_vector_type(4)));
typedef uint32_t u32x4 __attribute__((ext_vector_type(4)));

// fp32 -> bf16 round-to-nearest-even (used only in tiny build_w kernel)
__device__ __forceinline__ unsigned short f2b(float f) {
    union { float f; uint32_t u; } v; v.f = f;
    return (unsigned short)((v.u + 0x7FFFu + ((v.u >> 16) & 1u)) >> 16);
}

// pack two fp32 (as u32 bits) -> two bf16 with round-half-up (+0x8000).
// 3 VALU ops; carry into bit16 of `b` IS the round-up.
__device__ __forceinline__ uint32_t pk_bf16(uint32_t a, uint32_t b) {
    return ((a + 0x8000u) >> 16) | ((b + 0x8000u) & 0xFFFF0000u);
}

// async global->LDS, 16B per lane. LDS dest is wave-uniform base + lane*16.
__device__ __forceinline__ void async_ld16(const void* g, void* l) {
    __builtin_amdgcn_global_load_lds(
        (const __attribute__((address_space(1))) uint32_t*)g,
        (__attribute__((address_space(3))) uint32_t*)l, 16, 0, 0);
}

// ---------------------------------------------------------------------------
// Build W[o][c] = sum_b A[b,i,j]*B[b,k,m], o=i*64+k, c=j*64+m. bf16 RNE.
// ---------------------------------------------------------------------------
__global__ __launch_bounds__(256) void build_w_kernel(
    const float* __restrict__ A, const float* __restrict__ B,
    unsigned short* __restrict__ W)
{
    size_t idx = ((size_t)blockIdx.x * 256 + threadIdx.x) * 8;
    int o = (int)(idx >> 12);
    int c = (int)(idx & 4095);
    int i = o >> 6, k = o & 63;
    int j = c >> 6, m0 = c & 63;

    float acc[8];
#pragma unroll
    for (int t = 0; t < 8; ++t) acc[t] = 0.0f;
#pragma unroll
    for (int b = 0; b < 8; ++b) {
        float a = A[b * 4096 + i * 64 + j];
        const float4* bp = (const float4*)&B[b * 4096 + k * 64 + m0];
        float4 b0 = bp[0], b1 = bp[1];
        acc[0] += a * b0.x; acc[1] += a * b0.y;
        acc[2] += a * b0.z; acc[3] += a * b0.w;
        acc[4] += a * b1.x; acc[5] += a * b1.y;
        acc[6] += a * b1.z; acc[7] += a * b1.w;
    }
    ushort8 r;
#pragma unroll
    for (int t = 0; t < 8; ++t) r[t] = f2b(acc[t]);
    *(ushort8*)&W[idx] = r;
}

// ---------------------------------------------------------------------------
// GEMM: out[s,o] = sum_c x[s,c]*W[o,c] + bias[o]
// 128x128 tile, BK=32, 4 waves (2x2 of 64x64), 16x16x32 bf16 MFMA.
// A (x): fp32 global load -> round-half-up pack -> padded LDS (stride 40 bf16,
//        2-way banks = free).
// B (W): global_load_lds 16B with XOR column swizzle: physical chunk =
//        logical ^ ((row>>1)&3) -> frag reads 2-way = free.
// ---------------------------------------------------------------------------
#define AS_STRIDE 40   // bf16 elements per As row (80B, 16B-aligned, bank-spread)

__global__ __launch_bounds__(256, 2) void gemm_kernel(
    const float* __restrict__ xf,
    const unsigned short* __restrict__ W,
    const float* __restrict__ bias,
    float* __restrict__ out)
{
    __shared__ __align__(16) unsigned short As[128 * AS_STRIDE];
    __shared__ __align__(16) unsigned short Bs[128 * 32];

    const int tid = threadIdx.x;
    const int wave = tid >> 6;
    const int lane = tid & 63;
    const int quad = lane >> 4;
    const int l15 = lane & 15;
    const int wm = (wave >> 1) * 64;
    const int wn = (wave & 1) * 64;
    const size_t mbase = (size_t)blockIdx.y * 128;
    const int nbase = blockIdx.x * 128;

    // B staging: lane's swizzled source chunk (8 bf16 = 16B units)
    const int brow_in_issue = lane >> 2;                 // 0..15
    const int c_g = (lane & 3) ^ ((lane >> 3) & 3);      // physical->logical swizzle
    // A staging: thread -> one row-half (16 fp32)
    const int arow = tid >> 1;
    const int ahalf = tid & 1;
    const float* aptr = xf + (mbase + arow) * K_DIM + ahalf * 16;

    f32x4 acc[4][4];
#pragma unroll
    for (int a = 0; a < 4; ++a)
#pragma unroll
        for (int b = 0; b < 4; ++b)
            acc[a][b] = (f32x4){0.0f, 0.0f, 0.0f, 0.0f};

    for (int k0 = 0; k0 < K_DIM; k0 += 32) {
        // ---- stage B tile via async 16B, column-swizzled ----
#pragma unroll
        for (int t = 0; t < 2; ++t) {
            const int isn = wave * 2 + t;                // 0..7 (16 rows each)
            const int row = isn * 16 + brow_in_issue;
            async_ld16(&W[(size_t)(nbase + row) * K_DIM + k0 + c_g * 8],
                       &Bs[isn * 512]);
        }
        // ---- stage A tile: fp32 load + round-half-up pack -> padded LDS ----
        {
            const uint32_t* gp = (const uint32_t*)(aptr + k0);
            u32x4 v0 = ((const u32x4*)gp)[0];
            u32x4 v1 = ((const u32x4*)gp)[1];
            u32x4 v2 = ((const u32x4*)gp)[2];
            u32x4 v3 = ((const u32x4*)gp)[3];
            u32x4 lo, hi;
            lo[0] = pk_bf16(v0[0], v0[1]); lo[1] = pk_bf16(v0[2], v0[3]);
            lo[2] = pk_bf16(v1[0], v1[1]); lo[3] = pk_bf16(v1[2], v1[3]);
            hi[0] = pk_bf16(v2[0], v2[1]); hi[1] = pk_bf16(v2[2], v2[3]);
            hi[2] = pk_bf16(v3[0], v3[1]); hi[3] = pk_bf16(v3[2], v3[3]);
            uint32_t* wp = (uint32_t*)&As[arow * AS_STRIDE + ahalf * 16];
            *(u32x4*)wp = lo;
            *(u32x4*)(wp + 4) = hi;
        }
        __syncthreads();

        // ---- LDS -> frags -> MFMA ----
        short8 af[4], bf[4];
#pragma unroll
        for (int mt = 0; mt < 4; ++mt)
            af[mt] = *(const short8*)&As[(wm + mt * 16 + l15) * AS_STRIDE + quad * 8];
#pragma unroll
        for (int nt = 0; nt < 4; ++nt) {
            const int row = wn + nt * 16 + l15;          // tile row 0..127
            const int pchunk = quad ^ ((row >> 1) & 3);  // undo staging swizzle
            bf[nt] = *(const short8*)&Bs[row * 32 + pchunk * 8];
        }
#pragma unroll
        for (int mt = 0; mt < 4; ++mt)
#pragma unroll
            for (int nt = 0; nt < 4; ++nt)
                acc[mt][nt] = __builtin_amdgcn_mfma_f32_16x16x32_bf16(
                    af[mt], bf[nt], acc[mt][nt], 0, 0, 0);
        __syncthreads();
    }

    // ---- epilogue: C/D layout row=quad*4+r, col=lane&15; add bias ----
    float bv[4];
#pragma unroll
    for (int nt = 0; nt < 4; ++nt) bv[nt] = bias[nbase + wn + nt * 16 + l15];
#pragma unroll
    for (int mt = 0; mt < 4; ++mt) {
#pragma unroll
        for (int r = 0; r < 4; ++r) {
            const size_t row = mbase + wm + mt * 16 + quad * 4 + r;
            float* orow = out + row * N_DIM + nbase + wn + l15;
#pragma unroll
            for (int nt = 0; nt < 4; ++nt)
                orow[nt * 16] = acc[mt][nt][r] + bv[nt];
        }
    }
}

// ---------------------------------------------------------------------------
extern "C" void kernel_launch(void* const* d_in, const int* in_sizes, int n_in,
                              void* d_out, int out_size, void* d_ws, size_t ws_size,
                              hipStream_t stream)
{
    const float* x = (const float*)d_in[0];
    const float* A = (const float*)d_in[1];
    const float* B = (const float*)d_in[2];
    const float* bias = (const float*)d_in[3];
    float* out = (float*)d_out;

    unsigned short* Wb = (unsigned short*)d_ws;   // 32 MB bf16 W (rebuilt every call)

    build_w_kernel<<<(N_DIM * (size_t)K_DIM) / 8 / 256, 256, 0, stream>>>(A, B, Wb);
    gemm_kernel<<<dim3(N_DIM / 128, M_DIM / 128), 256, 0, stream>>>(
        x, Wb, bias, out);
}